// Round 4
// baseline (439.037 us; speedup 1.0000x reference)
//
#include <hip/hip_runtime.h>
#include <math.h>

namespace {
constexpr int NBINS = 8;
constexpr int HW = 512 * 512;
constexpr int HW4 = HW / 4;            // float4s per (b,c) plane
constexpr int PLANES = 16 * 3;         // B*C
constexpr int TPB = 256;
constexpr int IPT = 4;                 // float4s per thread
constexpr int XBLOCKS = HW4 / (TPB * IPT);   // 64 blocks per plane
// ln((double)1.01f); 1.01f == 1.0099999904632568359375
constexpr double LN_BASE = 0.0099503214108481;
// correctly-rounded powf(1.01f,z) > 1.0f  <=>  true value > 1 + 2^-24 (tie->even->1.0)
constexpr double KEEP_THRESH = 1.0 + 1.0 / 16777216.0;
// log2(1.01f) — value path only needs ~2e-2 accuracy
constexpr float LOG2_BASE = 0.014355293f;
// bins are uniform: edges -0.05 + k*0.1375, centers = edge + half-spacing.
// k* = floor((x+0.05)/0.1375) = nearest center = argmax z.  fp32 error ~1e-7 in
// x-units; misassignment only within that distance of an edge, where z << the
// keep-threshold (~6e-6) so the value is 0 from either bin -> bit-exact.
constexpr float INV_SPACING = 7.2727275f;   // fl32(1/0.1375)
constexpr float EDGE_OFF = 0.36363637f;     // fl32(0.05/0.1375)

typedef float v4f __attribute__((ext_vector_type(4)));

__device__ __forceinline__ float binval(float z) {
  if (!(z > 0.0f)) return 0.0f;
  if (z < 1.0e-5f) {
    // Near the fp32 rounding boundary of powf(1.01f, z) at 1.0: decide in double.
    double p = exp((double)z * LN_BASE);
    if (!(p > KEEP_THRESH)) return 0.0f;
  }
  return exp2f(z * LOG2_BASE);
}

// One full load+compute+store pass over this block's slice.  ACC: accumulate
// per-block bin sums (only the first pass does; stores are idempotent so the
// second pass writes identical bytes).
template <bool ACC>
__device__ __forceinline__ void pass(
    const float4* __restrict__ in, const float* __restrict__ centers,
    float w, int plane, int base, float* __restrict__ out,
    float sums[NBINS]) {
  float c[NBINS];
#pragma unroll
  for (int k = 0; k < NBINS; ++k) c[k] = centers[k];       // uniform scalar loads

  float4 x[IPT];
#pragma unroll
  for (int g = 0; g < IPT; ++g)
    x[g] = in[(size_t)plane * HW4 + base + g * TPB];

  int kk[IPT][4];
  float val[IPT][4];
#pragma unroll
  for (int g = 0; g < IPT; ++g) {
    const float px[4] = {x[g].x, x[g].y, x[g].z, x[g].w};
#pragma unroll
    for (int e = 0; e < 4; ++e) {
      const float t = fmaf(px[e], INV_SPACING, EDGE_OFF);
      int k = (int)t;                  // t >= 0.36 for x >= 0: trunc == floor
      k = k < 0 ? 0 : (k > NBINS - 1 ? NBINS - 1 : k);
      kk[g][e] = k;
      const float z = w - fabsf(px[e] - c[k]);
      val[g][e] = binval(z);
    }
  }

  v4f* const out2 = reinterpret_cast<v4f*>(out + PLANES * NBINS) +
                    (size_t)plane * NBINS * HW4;
#pragma unroll
  for (int k = 0; k < NBINS; ++k) {
#pragma unroll
    for (int g = 0; g < IPT; ++g) {
      v4f v;
#pragma unroll
      for (int e = 0; e < 4; ++e) {
        const float o = (kk[g][e] == k) ? val[g][e] : 0.0f;
        v[e] = o;
        if (ACC) sums[k] += o;
      }
      out2[(size_t)k * HW4 + base + g * TPB] = v;
    }
  }
}

template <bool USE_WS>
__device__ __forceinline__ void hist_body(
    const float4* __restrict__ in, const float* __restrict__ centers,
    const float* __restrict__ wptr, float* __restrict__ out,
    float* __restrict__ ws) {
  const int plane = blockIdx.y;                            // b*C + c
  const int base = blockIdx.x * (TPB * IPT) + threadIdx.x; // first float4 index
  const float w = wptr[0];

  float sums[NBINS];
#pragma unroll
  for (int k = 0; k < NBINS; ++k) sums[k] = 0.0f;

  // MEASUREMENT ROUND: run the identical pass twice inside one dispatch.
  // The memory clobber between passes forbids load-CSE across passes and
  // forbids dead-store elimination of pass 1's stores (outputs idempotent,
  // sums only accumulated in pass 1 -> results bit-identical).  Purpose:
  // (a) Δdur vs round 3 == one pass's true cost; (b) if the pass is really
  // ~180us, this dispatch (~360us) enters the top-5 and exposes its
  // FETCH_SIZE/WRITE_SIZE/VALUBusy/Occupancy counters for the first time.
  pass<true>(in, centers, w, plane, base, out, sums);
  asm volatile("" ::: "memory");
  pass<false>(in, centers, w, plane, base, out, sums);

  // block reduction: wave shuffle -> LDS across 4 waves
#pragma unroll
  for (int k = 0; k < NBINS; ++k) {
#pragma unroll
    for (int off = 32; off > 0; off >>= 1)
      sums[k] += __shfl_down(sums[k], off, 64);
  }
  __shared__ float part[TPB / 64][NBINS];
  const int lane = threadIdx.x & 63;
  const int wv = threadIdx.x >> 6;
  if (lane == 0) {
#pragma unroll
    for (int k = 0; k < NBINS; ++k) part[wv][k] = sums[k];
  }
  __syncthreads();
  if (threadIdx.x < NBINS) {
    const float s = (part[0][threadIdx.x] + part[1][threadIdx.x]) +
                    (part[2][threadIdx.x] + part[3][threadIdx.x]);
    if (USE_WS) {
      ws[((size_t)plane * XBLOCKS + blockIdx.x) * NBINS + threadIdx.x] = s;
    } else {
      atomicAdd(out + plane * NBINS + threadIdx.x, s * (1.0f / (float)HW));
    }
  }
}
}  // namespace

__global__ __launch_bounds__(TPB) void hist_kernel_ws(
    const float4* __restrict__ in, const float* __restrict__ centers,
    const float* __restrict__ wptr, float* __restrict__ out,
    float* __restrict__ ws) {
  hist_body<true>(in, centers, wptr, out, ws);
}

__global__ __launch_bounds__(TPB) void hist_kernel_atomic(
    const float4* __restrict__ in, const float* __restrict__ centers,
    const float* __restrict__ wptr, float* __restrict__ out) {
  hist_body<false>(in, centers, wptr, out, nullptr);
}

// 384 threads: out[plane*8+k] = (sum_b ws[plane][b][k]) / HW.  Deterministic,
// overwrites the poisoned one_d region fully (no memset needed).
__global__ __launch_bounds__(64) void reduce_kernel(
    const float* __restrict__ ws, float* __restrict__ out) {
  const int t = blockIdx.x * 64 + threadIdx.x;
  if (t >= PLANES * NBINS) return;
  const int plane = t / NBINS, k = t % NBINS;
  float s = 0.0f;
  for (int b = 0; b < XBLOCKS; ++b)
    s += ws[((size_t)plane * XBLOCKS + b) * NBINS + k];
  out[t] = s * (1.0f / (float)HW);
}

extern "C" void kernel_launch(void* const* d_in, const int* in_sizes, int n_in,
                              void* d_out, int out_size, void* d_ws, size_t ws_size,
                              hipStream_t stream) {
  const float4* in = (const float4*)d_in[0];
  const float* centers = (const float*)d_in[1];
  const float* width = (const float*)d_in[2];
  float* out = (float*)d_out;
  const size_t ws_needed = (size_t)PLANES * XBLOCKS * NBINS * sizeof(float);
  if (d_ws != nullptr && ws_size >= ws_needed) {
    float* ws = (float*)d_ws;
    hist_kernel_ws<<<dim3(XBLOCKS, PLANES), TPB, 0, stream>>>(
        in, centers, width, out, ws);
    reduce_kernel<<<dim3((PLANES * NBINS + 63) / 64), 64, 0, stream>>>(ws, out);
  } else {
    // fallback: legacy atomic path
    (void)hipMemsetAsync(d_out, 0, PLANES * NBINS * sizeof(float), stream);
    hist_kernel_atomic<<<dim3(XBLOCKS, PLANES), TPB, 0, stream>>>(
        in, centers, width, out);
  }
}

// Round 5
// 428.631 us; speedup vs baseline: 1.0243x; 1.0243x over previous
//
#include <hip/hip_runtime.h>
#include <math.h>

// FINAL ARTIFACT — harness-floor regime.
// Round-4 experiment: duplicating the entire load/compute/store pass inside the
// dispatch changed dur_us by +0.03us (439.01 -> 439.04) and the doubled kernel
// still ran under the ~252us top-5 cutoff.  The timed pipeline is saturated by
// fixed harness HBM traffic (1.61 GB poison fill / iter at a measured
// 6.2-6.4 TB/s = the achievable ceiling, plus verification movement); the
// kernel's mandatory 453 MB is fully hidden.  Structure below = round-0's
// (best single measurement, 430.6us) + the bit-exact single-exp2 compute path.
namespace {
constexpr int NBINS = 8;
constexpr int HW = 512 * 512;
constexpr int HW4 = HW / 4;            // float4s per (b,c) plane
constexpr int PLANES = 16 * 3;         // B*C
constexpr int TPB = 256;
// ln((double)1.01f); 1.01f == 1.0099999904632568359375
constexpr double LN_BASE = 0.0099503214108481;
// correctly-rounded powf(1.01f,z) > 1.0f  <=>  true value > 1 + 2^-24 (tie->even->1.0)
constexpr double KEEP_THRESH = 1.0 + 1.0 / 16777216.0;
// log2(1.01f) — value path only needs ~2e-2 accuracy
constexpr float LOG2_BASE = 0.014355293f;
// bins are uniform: edges -0.05 + k*0.1375, centers = edge + half-spacing.
// k* = floor((x+0.05)/0.1375) = nearest center = argmax_k z_k.  fp32 error in
// the fma+trunc is ~1e-7 in x-units; misassignment can only occur within that
// distance of a bin edge, where z < ~2e-7 << keep-threshold (~6e-6), so the
// output value is 0 from either bin -> bit-identical to evaluating all 8 bins.
// (At most ONE bin per pixel passes the keep test: z_k + z_j <= 2w - |c_k-c_j|
// + fp error < 1.2e-5 for adjacent bins, and the threshold needs z > ~6e-6.)
constexpr float INV_SPACING = 7.2727275f;   // fl32(1/0.1375)
constexpr float EDGE_OFF = 0.36363637f;     // fl32(0.05/0.1375)

typedef float v4f __attribute__((ext_vector_type(4)));

__device__ __forceinline__ float binval(float z) {
  if (!(z > 0.0f)) return 0.0f;
  if (z < 1.0e-5f) {
    // Near the fp32 rounding boundary of powf(1.01f, z) at 1.0: decide in double.
    double p = exp((double)z * LN_BASE);
    if (!(p > KEEP_THRESH)) return 0.0f;
  }
  return exp2f(z * LOG2_BASE);
}
}  // namespace

__global__ __launch_bounds__(TPB) void hist_kernel(
    const float4* __restrict__ in, const float* __restrict__ centers,
    const float* __restrict__ wptr, float* __restrict__ out) {
  const int plane = blockIdx.y;                    // b*C + c
  const int i4 = blockIdx.x * TPB + threadIdx.x;   // float4 index in plane
  const float w = wptr[0];
  float c[NBINS];
#pragma unroll
  for (int k = 0; k < NBINS; ++k) c[k] = centers[k];  // uniform scalar loads

  const float4 x = in[(size_t)plane * HW4 + i4];
  const float px[4] = {x.x, x.y, x.z, x.w};

  // Direct bin index + single binval per pixel (bit-exact vs 8-way; see above).
  int kk[4];
  float val[4];
#pragma unroll
  for (int e = 0; e < 4; ++e) {
    const float t = fmaf(px[e], INV_SPACING, EDGE_OFF);
    int k = (int)t;                   // t >= 0.36 for x >= 0: trunc == floor
    k = k < 0 ? 0 : (k > NBINS - 1 ? NBINS - 1 : k);
    kk[e] = k;
    const float z = w - fabsf(px[e] - c[k]);
    val[e] = binval(z);
  }

  v4f* const out2 = reinterpret_cast<v4f*>(out + PLANES * NBINS) +
                    (size_t)plane * NBINS * HW4 + i4;
  float sums[NBINS];
#pragma unroll
  for (int k = 0; k < NBINS; ++k) {
    v4f v;
#pragma unroll
    for (int e = 0; e < 4; ++e) v[e] = (kk[e] == k) ? val[e] : 0.0f;
    __builtin_nontemporal_store(v, out2 + (size_t)k * HW4);
    sums[k] = (v[0] + v[1]) + (v[2] + v[3]);
  }

  // block reduction: wave shuffle -> LDS across 4 waves -> 8 atomics/block
#pragma unroll
  for (int k = 0; k < NBINS; ++k) {
#pragma unroll
    for (int off = 32; off > 0; off >>= 1)
      sums[k] += __shfl_down(sums[k], off, 64);
  }
  __shared__ float part[TPB / 64][NBINS];
  const int lane = threadIdx.x & 63;
  const int wv = threadIdx.x >> 6;
  if (lane == 0) {
#pragma unroll
    for (int k = 0; k < NBINS; ++k) part[wv][k] = sums[k];
  }
  __syncthreads();
  if (threadIdx.x < NBINS) {
    float s = (part[0][threadIdx.x] + part[1][threadIdx.x]) +
              (part[2][threadIdx.x] + part[3][threadIdx.x]);
    atomicAdd(out + plane * NBINS + threadIdx.x, s * (1.0f / (float)HW));
  }
}

extern "C" void kernel_launch(void* const* d_in, const int* in_sizes, int n_in,
                              void* d_out, int out_size, void* d_ws, size_t ws_size,
                              hipStream_t stream) {
  const float4* in = (const float4*)d_in[0];
  const float* centers = (const float*)d_in[1];
  const float* width = (const float*)d_in[2];
  float* out = (float*)d_out;
  // one_d region (first 384 floats) accumulates via atomics — zero it each call
  (void)hipMemsetAsync(d_out, 0, PLANES * NBINS * sizeof(float), stream);
  hist_kernel<<<dim3(HW4 / TPB, PLANES), TPB, 0, stream>>>(in, centers, width, out);
}